// Round 12
// baseline (756.135 us; speedup 1.0000x reference)
//
#include <hip/hip_runtime.h>

// ComplexAttention: B=4, S=2048, D=1024. Reduces to single-head attention with
// head_dim 2*D=2048:  Q/K/V = X@W^T+b ; S = Q@K^T/32 ; P = softmax(S) ; O = P@V ;
// out = O@Wo^T + bo.
// R12: A-operand bypasses LDS entirely -- fragments loaded global->VGPR directly
// (frag pattern = 16 rows x 64B contiguous = coalesced; 32KB A-tile is L1-resident;
// 4x wave redundancy served by L1/L2, HBM traffic unchanged).  LDS holds only B
// (stage 32KB + read 64KB per K-tile ~ 900 cyc, off critical path).  R11 diagnosis:
// 192 b128 LDS reads/K-tile (~2300cyc) serialized with MFMA (2483cyc) -> 43% util
// plateau independent of barrier structure.

typedef short  bf16x8 __attribute__((ext_vector_type(8)));
typedef float  f32x4  __attribute__((ext_vector_type(4)));
typedef unsigned short u16;

typedef __attribute__((address_space(3))) void       lds_void;
typedef const __attribute__((address_space(1))) void g_void;

__device__ __forceinline__ u16 f2bf(float f) {
  union { float f; unsigned u; } v; v.f = f;
  unsigned r = v.u + 0x7FFFu + ((v.u >> 16) & 1u);   // round-to-nearest-even
  return (u16)(r >> 16);
}

// ---------------- fp32 -> bf16 convert (vectorized) ----------------
__global__ __launch_bounds__(256) void cvt_f32_bf16(const float* __restrict__ in,
                                                    u16* __restrict__ out, int n4) {
  int i = blockIdx.x * 256 + threadIdx.x;
  if (i >= n4) return;
  const float4 v = ((const float4*)in)[i];
  union { u16 us[4]; unsigned long long ll; } u;
  u.us[0] = f2bf(v.x); u.us[1] = f2bf(v.y); u.us[2] = f2bf(v.z); u.us[3] = f2bf(v.w);
  ((unsigned long long*)out)[i] = u.ll;
}

// ---------------- 256x(NH*128) NT GEMM: A direct-from-global, B via LDS --------
// C[m,n] = alpha * sum_k A[m,k]*B[n,k] (+ bias[n]).  A,B bf16 row-major (K contig).
// CMODE: 0 = fp32 C, 1 = bf16 C, 2 = bf16 transposed-V write Vt[b][n][t].
// 512 thr = 8 waves (2M x 4N); per-wave 128x(NH*32); BK=64; B dbuf XOR-swizzled.
// Per K-tile: {rd B-frags (LDS); stage B(t+1); fence; vload afB(half1);
//             MM half0 x(NH*16); vload afA(t+1) prefetch; MM half1; fence;
//             vmcnt(8) [drains stage, keeps prefetch]; barrier}
// RAW: B(t) staged prev tile, drained by prev vmcnt(8) (stage is never among the
// 8 newest: fences pin stage -> afB -> afA' issue order) + barrier.  WAR: restage
// of buf d in tile t+1 is post-barrier; tile-t B-reads were lgkm-consumed by MMs.
// A-regs: compiler-tracked (auto vmcnt before consuming MFMA).
template<int CMODE, bool BIAS, int NH>
__global__ __launch_bounds__(512, 2) void gemm256(const u16* __restrict__ A,
                                                  const u16* __restrict__ B,
                                                  void* __restrict__ Cv,
                                                  const float* __restrict__ bias,
                                                  int K, int lda, int ldb, int ldc,
                                                  long bsA, long bsB, long bsC,
                                                  float alpha)
{
  __shared__ u16 sm[32768];                  // B only: [2][<=256][64]
  const int bz = blockIdx.z;
  const u16* Ab = A + (long)bz * bsA;
  const u16* Bb = B + (long)bz * bsB;
  const int m0 = blockIdx.y * 256, n0 = blockIdx.x * (NH * 128);
  const int tid = threadIdx.x, lane = tid & 63, w = tid >> 6;
  const int wmr = w >> 2, wnr = w & 3;
  const int fr = lane & 15, ko = lane >> 4;

  f32x4 acc[8][2 * NH] = {};
  bf16x8 afA[8], afB[8], bfA[4], bfB[4];

  auto STAGE_B = [&](int dbuf, int half, int t) {
    const int r0 = n0 + half * 128;
    u16* lb = sm + dbuf * 16384 + half * 8192;
#pragma unroll
    for (int q = 0; q < 2; ++q) {
      const int slot = q * 512 + w * 64 + lane;
      const int rl = slot >> 3, cc = slot & 7;
      const int c = cc ^ (rl & 7);
      __builtin_amdgcn_global_load_lds(
          (g_void*)(Bb + (long)(r0 + rl) * ldb + t * 64 + c * 8),
          (lds_void*)(lb + q * 4096 + w * 512), 16, 0, 0);
    }
  };
  // A fragments straight from global: row = m0+wmr*128+mh*64+mi*16+fr,
  // elem col = t*64 + kk*32 + ko*8  (16B per lane, 16 rows x 64B per instr).
  auto LDA_g = [&](bf16x8* dst, int mh, int t) {
    const u16* base = Ab + (long)(m0 + wmr * 128 + mh * 64 + fr) * lda + t * 64 + ko * 8;
#pragma unroll
    for (int mi = 0; mi < 4; ++mi)
#pragma unroll
      for (int kk = 0; kk < 2; ++kk)
        dst[mi * 2 + kk] = *(const bf16x8*)(base + (long)(mi * 16) * lda + kk * 32);
  };
  auto LDB_f = [&](bf16x8* dst, int dbuf, int nh) {
#pragma unroll
    for (int ni = 0; ni < 2; ++ni)
#pragma unroll
      for (int kk = 0; kk < 2; ++kk) {
        const int r = wnr * (NH * 32) + nh * 32 + ni * 16 + fr;
        const int c = kk * 4 + ko;
        dst[ni * 2 + kk] = *(const bf16x8*)(sm + dbuf * 16384 + r * 64 + ((c ^ (r & 7)) * 8));
      }
  };
  auto MM = [&](const bf16x8* af, const bf16x8* bf, int mb, int nb) {
    __builtin_amdgcn_s_setprio(1);
#pragma unroll
    for (int mi = 0; mi < 4; ++mi)
#pragma unroll
      for (int ni = 0; ni < 2; ++ni)
#pragma unroll
        for (int kk = 0; kk < 2; ++kk)
          acc[mb + mi][nb + ni] = __builtin_amdgcn_mfma_f32_16x16x32_bf16(
              af[mi * 2 + kk], bf[ni * 2 + kk], acc[mb + mi][nb + ni], 0, 0, 0);
    __builtin_amdgcn_s_setprio(0);
  };

  const int nt = K >> 6;

  // prologue: B(0) -> buf0; afA(0) prefetch; drain stage (keep afA's 8).
  STAGE_B(0, 0, 0);
  if constexpr (NH == 2) STAGE_B(0, 1, 0);
  LDA_g(afA, 0, 0);
  __builtin_amdgcn_sched_barrier(0);
  asm volatile("s_waitcnt vmcnt(8)" ::: "memory");
  asm volatile("s_barrier" ::: "memory");

  for (int t = 0; t < nt; ++t) {
    const int d = t & 1;
    const bool pre = (t + 1 < nt);
    // B-frag reads for this tile + stage next tile's B
    LDB_f(bfA, d, 0);
    if constexpr (NH == 2) LDB_f(bfB, d, 1);
    if (pre) {
      STAGE_B(d ^ 1, 0, t + 1);
      if constexpr (NH == 2) STAGE_B(d ^ 1, 1, t + 1);
    }
    __builtin_amdgcn_sched_barrier(0);       // pin stage before A-loads
    LDA_g(afB, 1, t);                        // half1 A (used after half0 MMs)
    MM(afA, bfA, 0, 0);
    if constexpr (NH == 2) MM(afA, bfB, 0, 2);
    if (pre) LDA_g(afA, 0, t + 1);           // prefetch next tile half0
    MM(afB, bfA, 4, 0);
    if constexpr (NH == 2) MM(afB, bfB, 4, 2);
    __builtin_amdgcn_sched_barrier(0);       // pin everything above the wait
    if (pre) asm volatile("s_waitcnt vmcnt(8)" ::: "memory");  // drains stage+afB
    else     asm volatile("s_waitcnt vmcnt(0)" ::: "memory");
    asm volatile("s_barrier" ::: "memory");
  }

  // epilogue: C/D frag layout col=lane&15, row=(lane>>4)*4+r  (m89-verified)
  const int col = lane & 15, rb = (lane >> 4) * 4;
#pragma unroll
  for (int mi = 0; mi < 8; ++mi) {
#pragma unroll
    for (int ni = 0; ni < 2 * NH; ++ni) {
      const int mg = m0 + wmr * 128 + mi * 16 + rb;
      const int ng = n0 + wnr * (NH * 32) + ni * 16 + col;
      const float bvv = BIAS ? bias[ng] : 0.0f;
      if constexpr (CMODE == 2) {
        u16* Cc = (u16*)Cv;
        const long bb = mg >> 11;
        const int  t  = mg & 2047;
        union { u16 us[4]; unsigned long long ll; } u;
#pragma unroll
        for (int r = 0; r < 4; ++r) u.us[r] = f2bf(acc[mi][ni][r] * alpha + bvv);
        *(unsigned long long*)(Cc + bb * 4194304 + (long)ng * 2048 + t) = u.ll;
      } else if constexpr (CMODE == 1) {
        u16* Cc = (u16*)Cv + (long)bz * bsC;
#pragma unroll
        for (int r = 0; r < 4; ++r)
          Cc[(long)(mg + r) * ldc + ng] = f2bf(acc[mi][ni][r] * alpha + bvv);
      } else {
        float* Cf = (float*)Cv + (long)bz * bsC;
#pragma unroll
        for (int r = 0; r < 4; ++r)
          Cf[(long)(mg + r) * ldc + ng] = acc[mi][ni][r] * alpha + bvv;
      }
    }
  }
}

// ---------------- row softmax: fp32 scores row (2048) -> bf16 P in-place --------
__global__ __launch_bounds__(256) void softmax_rows(float* __restrict__ Sc) {
  const int tid = threadIdx.x;
  const long row = blockIdx.x;
  float* srow = Sc + row * 2048;
  const float4 v0 = ((const float4*)srow)[tid * 2];
  const float4 v1 = ((const float4*)srow)[tid * 2 + 1];
  float mx = fmaxf(fmaxf(fmaxf(v0.x, v0.y), fmaxf(v0.z, v0.w)),
                   fmaxf(fmaxf(v1.x, v1.y), fmaxf(v1.z, v1.w)));
  __shared__ float red[8];
  const int lane = tid & 63, wid = tid >> 6;
#pragma unroll
  for (int off = 32; off; off >>= 1) mx = fmaxf(mx, __shfl_down(mx, off));
  if (!lane) red[wid] = mx;
  __syncthreads();
  mx = fmaxf(fmaxf(red[0], red[1]), fmaxf(red[2], red[3]));
  float e[8];
  e[0] = __expf(v0.x - mx); e[1] = __expf(v0.y - mx);
  e[2] = __expf(v0.z - mx); e[3] = __expf(v0.w - mx);
  e[4] = __expf(v1.x - mx); e[5] = __expf(v1.y - mx);
  e[6] = __expf(v1.z - mx); e[7] = __expf(v1.w - mx);
  float s = e[0] + e[1] + e[2] + e[3] + e[4] + e[5] + e[6] + e[7];
#pragma unroll
  for (int off = 32; off; off >>= 1) s += __shfl_down(s, off);
  if (!lane) red[4 + wid] = s;
  __syncthreads();
  s = red[4] + red[5] + red[6] + red[7];
  const float inv = 1.0f / s;
  union { u16 us[8]; int4 v; } u;
#pragma unroll
  for (int j = 0; j < 8; ++j) u.us[j] = f2bf(e[j] * inv);
  ((int4*)srow)[tid] = u.v;
}

extern "C" void kernel_launch(void* const* d_in, const int* in_sizes, int n_in,
                              void* d_out, int out_size, void* d_ws, size_t ws_size,
                              hipStream_t stream) {
  const float* X  = (const float*)d_in[0];
  const float* Wq = (const float*)d_in[1];
  const float* bq = (const float*)d_in[2];
  const float* Wk = (const float*)d_in[3];
  const float* bk = (const float*)d_in[4];
  const float* Wv = (const float*)d_in[5];
  const float* bv = (const float*)d_in[6];
  const float* Wo = (const float*)d_in[7];
  const float* bo = (const float*)d_in[8];
  float* out = (float*)d_out;

  char* w = (char*)d_ws;
  u16* Xb  = (u16*)w; w += (size_t)8192 * 1024 * 2;
  u16* Wqb = (u16*)w; w += (size_t)2048 * 1024 * 2;
  u16* Wkb = (u16*)w; w += (size_t)2048 * 1024 * 2;
  u16* Wvb = (u16*)w; w += (size_t)2048 * 1024 * 2;
  u16* Wob = (u16*)w; w += (size_t)1024 * 2048 * 2;
  u16* Qb  = (u16*)w; w += (size_t)8192 * 2048 * 2;
  u16* Kb  = (u16*)w; w += (size_t)8192 * 2048 * 2;
  u16* Vt  = (u16*)w; w += (size_t)8192 * 2048 * 2;   // [4][2048 d][2048 t]
  u16* AO  = (u16*)w; w += (size_t)8192 * 2048 * 2;
  float* Sc = (float*)w; w += (size_t)4 * 2048 * 2048 * 4;
  if ((size_t)(w - (char*)d_ws) > ws_size) return;

  cvt_f32_bf16<<<8192, 256, 0, stream>>>(X,  Xb,  8192 * 1024 / 4);
  cvt_f32_bf16<<<2048, 256, 0, stream>>>(Wq, Wqb, 2048 * 1024 / 4);
  cvt_f32_bf16<<<2048, 256, 0, stream>>>(Wk, Wkb, 2048 * 1024 / 4);
  cvt_f32_bf16<<<2048, 256, 0, stream>>>(Wv, Wvb, 2048 * 1024 / 4);
  cvt_f32_bf16<<<2048, 256, 0, stream>>>(Wo, Wob, 1024 * 2048 / 4);

  // projections: M=8192, N=2048, K=1024
  gemm256<1, true, 2><<<dim3(8, 32, 1), 512, 0, stream>>>(Xb, Wqb, Qb, bq,
      1024, 1024, 1024, 2048, 0, 0, 0, 1.0f);
  gemm256<1, true, 2><<<dim3(8, 32, 1), 512, 0, stream>>>(Xb, Wkb, Kb, bk,
      1024, 1024, 1024, 2048, 0, 0, 0, 1.0f);
  gemm256<2, true, 2><<<dim3(8, 32, 1), 512, 0, stream>>>(Xb, Wvb, Vt, bv,
      1024, 1024, 1024, 0, 0, 0, 0, 1.0f);

  // scores: per-batch 2048x2048, K=2048, alpha = 1/sqrt(1024)
  gemm256<0, false, 2><<<dim3(8, 8, 4), 512, 0, stream>>>(Qb, Kb, Sc, nullptr,
      2048, 2048, 2048, 2048, 4194304, 4194304, 4194304, 0.03125f);

  softmax_rows<<<8192, 256, 0, stream>>>(Sc);

  // O = P @ Vt^T : A = bf16 P view of Sc (lda 4096)
  gemm256<1, false, 2><<<dim3(8, 8, 4), 512, 0, stream>>>((u16*)Sc, Vt, AO, nullptr,
      2048, 4096, 2048, 2048, 8388608, 4194304, 4194304, 1.0f);

  // out = AO @ Wo^T + bo : M=8192, N=1024, K=2048, fp32 out (NH=1: 256 blocks)
  gemm256<0, true, 1><<<dim3(8, 32, 1), 512, 0, stream>>>(AO, Wob, out, bo,
      2048, 2048, 2048, 1024, 0, 0, 0, 1.0f);
}

// Round 13
// 548.144 us; speedup vs baseline: 1.3794x; 1.3794x over previous
//
#include <hip/hip_runtime.h>

// ComplexAttention: B=4, S=2048, D=1024. Reduces to single-head attention with
// head_dim 2*D=2048:  Q/K/V = X@W^T+b ; S = Q@K^T/32 ; P = softmax(S) ; O = P@V ;
// out = O@Wo^T + bo.
// R13: faithful m201-style 8-phase with reads ONE PHASE AHEAD of their MFMA cluster
// (the unconfounded missing ingredient; R7's try had a different stage map + spill).
// Stage map = R2's (proven safe); drains moved 1 phase earlier: vmcnt(2)@p3 /
// vmcnt(4)@p7 so p4/p8 can read the freshly-drained buffer.  bfA held across its
// two uses (no re-read -> no same-phase read/restage).  Live peak 28 b128 = 112
// arch VGPR.  MM = lgkm0 + sched_barrier(0) (rule 18) + setprio + 16 MFMA.

typedef short  bf16x8 __attribute__((ext_vector_type(8)));
typedef float  f32x4  __attribute__((ext_vector_type(4)));
typedef unsigned short u16;

typedef __attribute__((address_space(3))) void       lds_void;
typedef const __attribute__((address_space(1))) void g_void;

#define BARA() asm volatile("s_barrier" ::: "memory")

__device__ __forceinline__ u16 f2bf(float f) {
  union { float f; unsigned u; } v; v.f = f;
  unsigned r = v.u + 0x7FFFu + ((v.u >> 16) & 1u);   // round-to-nearest-even
  return (u16)(r >> 16);
}

// ---------------- fp32 -> bf16 convert (vectorized) ----------------
__global__ __launch_bounds__(256) void cvt_f32_bf16(const float* __restrict__ in,
                                                    u16* __restrict__ out, int n4) {
  int i = blockIdx.x * 256 + threadIdx.x;
  if (i >= n4) return;
  const float4 v = ((const float4*)in)[i];
  union { u16 us[4]; unsigned long long ll; } u;
  u.us[0] = f2bf(v.x); u.us[1] = f2bf(v.y); u.us[2] = f2bf(v.z); u.us[3] = f2bf(v.w);
  ((unsigned long long*)out)[i] = u.ll;
}

// ======== 256x256 8-phase NT GEMM, reads 1 phase ahead (m201 port) ========
// Phase p: [ds_reads for phase p+1's MFMA] [stage half-tile(s)] [vmcnt if due]
//          [BAR] [lgkm0+SB0] [setprio1; 16 MFMA; setprio0] [BAR]
// Reads:  p8'/pro:{afA,bfA0}(b0)  p1:bfB(b0,1)  p2:afB(b0,1)  p4:{afA,bfA1}(b1)
//         p5:bfB(b1,1)  p6:afB(b1,1)
// MFMA:   p1 Q00(afA,bfA0) p2 Q01(afA,bfB) p3 Q11(afB,bfB) p4 Q10(afB,bfA0)
//         p5 Q00(afA,bfA1) p6 Q01(afA,bfB) p7 Q11(afB,bfB) p8 Q10(afB,bfA1)
// Stages: p1:A1(t1)b1  p3:B0(tn)b0  p4:B1,A0(tn)b0  p5:A1(tn)b0
//         p6:B0(tn+1)b1  p7:B1(tn+1)b1  p8:A0(tn+1)b1
// vmcnt:  p3: pre?2:0 (drains b1's 8: p6',p7',p8',p1)  -> p4 reads b1 safe
//         p7: pre?4:0 (drains b0's 8: p3,p4,p5)        -> p8 reads b0 safe
// WAR: every frag captured >=2 barriers before its region restage (derived).
template<int CMODE, bool BIAS>
__global__ __launch_bounds__(512, 2) void gemm8p(const u16* __restrict__ A,
                                                 const u16* __restrict__ B,
                                                 void* __restrict__ Cv,
                                                 const float* __restrict__ bias,
                                                 int K, int lda, int ldb, int ldc,
                                                 long bsA, long bsB, long bsC,
                                                 float alpha)
{
  __shared__ u16 sm[65536];                  // A: [2][256][64] @ 0 ; B @ 32768
  const int bz = blockIdx.z;
  const u16* Ab = A + (long)bz * bsA;
  const u16* Bb = B + (long)bz * bsB;
  const int m0 = blockIdx.y * 256, n0 = blockIdx.x * 256;
  const int tid = threadIdx.x, lane = tid & 63, w = tid >> 6;
  const int wmr = w >> 2, wnr = w & 3;
  const int fr = lane & 15, ko = lane >> 4;

  f32x4 acc[8][4] = {};
  bf16x8 afA[8], afB[8], bfB[4], bfA0[4], bfA1[4];

  auto STAGE = [&](int dbuf, int half, int t, bool isA) {
    const u16* src = isA ? Ab : Bb;
    const int ld = isA ? lda : ldb;
    const int r0 = (isA ? m0 : n0) + half * 128;
    u16* lb = sm + (isA ? 0 : 32768) + dbuf * 16384 + half * 8192;
#pragma unroll
    for (int q = 0; q < 2; ++q) {
      const int slot = q * 512 + w * 64 + lane;
      const int rl = slot >> 3, cc = slot & 7;
      const int c = cc ^ (rl & 7);
      __builtin_amdgcn_global_load_lds(
          (g_void*)(src + (long)(r0 + rl) * ld + t * 64 + c * 8),
          (lds_void*)(lb + q * 4096 + w * 512), 16, 0, 0);
    }
  };
  auto LDA_f = [&](bf16x8* dst, int dbuf, int mh) {
#pragma unroll
    for (int mi = 0; mi < 4; ++mi)
#pragma unroll
      for (int kk = 0; kk < 2; ++kk) {
        const int r = wmr * 128 + mh * 64 + mi * 16 + fr;
        const int c = kk * 4 + ko;
        dst[mi * 2 + kk] = *(const bf16x8*)(sm + dbuf * 16384 + r * 64 + ((c ^ (r & 7)) * 8));
      }
  };
  auto LDB_f = [&](bf16x8* dst, int dbuf, int nh) {
#pragma unroll
    for (int ni = 0; ni < 2; ++ni)
#pragma unroll
      for (int kk = 0; kk < 2; ++kk) {
        const int r = wnr * 64 + nh * 32 + ni * 16 + fr;
        const int c = kk * 4 + ko;
        dst[ni * 2 + kk] = *(const bf16x8*)(sm + 32768 + dbuf * 16384 + r * 64 + ((c ^ (r & 7)) * 8));
      }
  };
  auto MM = [&](const bf16x8* af, const bf16x8* bf, int mb, int nb) {
    asm volatile("s_waitcnt lgkmcnt(0)" ::: "memory");
    __builtin_amdgcn_sched_barrier(0);       // rule 18: pin MFMA after the lgkm wait
    __builtin_amdgcn_s_setprio(1);
#pragma unroll
    for (int mi = 0; mi < 4; ++mi)
#pragma unroll
      for (int ni = 0; ni < 2; ++ni)
#pragma unroll
        for (int kk = 0; kk < 2; ++kk)
          acc[mb + mi][nb + ni] = __builtin_amdgcn_mfma_f32_16x16x32_bf16(
              af[mi * 2 + kk], bf[ni * 2 + kk], acc[mb + mi][nb + ni], 0, 0, 0);
    __builtin_amdgcn_s_setprio(0);
  };

  const int nt = K >> 6, niter = nt >> 1;

  // prologue: b0 full (t0=0) + b1 {B0,B1,A0} (t1=1); drain b0; pre-read Q00 frags.
  STAGE(0, 0, 0, true);  STAGE(0, 1, 0, true);
  STAGE(0, 0, 0, false); STAGE(0, 1, 0, false);
  STAGE(1, 0, 1, false); STAGE(1, 1, 1, false);
  STAGE(1, 0, 1, true);
  asm volatile("s_waitcnt vmcnt(6)" ::: "memory");
  BARA();
  LDA_f(afA, 0, 0); LDB_f(bfA0, 0, 0);

  for (int j = 0; j < niter; ++j) {
    const bool pre = (j + 1 < niter);
    const int t1 = 2 * j + 1, tn = 2 * j + 2;
    // p1: rd bfB(b0,1) | stage A1(t1)->b1 | MM Q00(t0)
    LDB_f(bfB, 0, 1);
    STAGE(1, 1, t1, true);
    BARA(); MM(afA, bfA0, 0, 0); BARA();
    // p2: rd afB(b0,1) | MM Q01(t0)
    LDA_f(afB, 0, 1);
    BARA(); MM(afA, bfB, 0, 2); BARA();
    // p3: stage B0(tn)->b0 | vmcnt(2|0) drains b1 | MM Q11(t0)
    if (pre) { STAGE(0, 0, tn, false); asm volatile("s_waitcnt vmcnt(2)" ::: "memory"); }
    else     { asm volatile("s_waitcnt vmcnt(0)" ::: "memory"); }
    BARA(); MM(afB, bfB, 4, 2); BARA();
    // p4: rd afA,bfA1(b1,0) | stage B1(tn),A0(tn)->b0 | MM Q10(t0)
    LDA_f(afA, 1, 0); LDB_f(bfA1, 1, 0);
    if (pre) { STAGE(0, 1, tn, false); STAGE(0, 0, tn, true); }
    BARA(); MM(afB, bfA0, 4, 0); BARA();
    // p5: rd bfB(b1,1) | stage A1(tn)->b0 | MM Q00(t1)
    LDB_f(bfB, 1, 1);
    if (pre) STAGE(0, 1, tn, true);
    BARA(); MM(afA, bfA1, 0, 0); BARA();
    // p6: rd afB(b1,1) | stage B0(tn+1)->b1 | MM Q01(t1)
    LDA_f(afB, 1, 1);
    if (pre) STAGE(1, 0, tn + 1, false);
    BARA(); MM(afA, bfB, 0, 2); BARA();
    // p7: stage B1(tn+1)->b1 | vmcnt(4|0) drains b0(tn) | MM Q11(t1)
    if (pre) { STAGE(1, 1, tn + 1, false); asm volatile("s_waitcnt vmcnt(4)" ::: "memory"); }
    else     { asm volatile("s_waitcnt vmcnt(0)" ::: "memory"); }
    BARA(); MM(afB, bfB, 4, 2); BARA();
    // p8: rd afA,bfA0(b0,tn) | stage A0(tn+1)->b1 | MM Q10(t1)
    if (pre) {
      LDA_f(afA, 0, 0); LDB_f(bfA0, 0, 0);
      STAGE(1, 0, tn + 1, true);
    }
    BARA(); MM(afB, bfA1, 4, 0); BARA();
  }

  // epilogue: C/D frag layout col=lane&15, row=(lane>>4)*4+r  (m89-verified)
  const int col = lane & 15, rb = (lane >> 4) * 4;
#pragma unroll
  for (int mi = 0; mi < 8; ++mi) {
#pragma unroll
    for (int ni = 0; ni < 4; ++ni) {
      const int mg = m0 + wmr * 128 + mi * 16 + rb;
      const int ng = n0 + wnr * 64 + ni * 16 + col;
      const float bvv = BIAS ? bias[ng] : 0.0f;
      if constexpr (CMODE == 2) {
        u16* Cc = (u16*)Cv;
        const long bb = mg >> 11;
        const int  t  = mg & 2047;
        union { u16 us[4]; unsigned long long ll; } u;
#pragma unroll
        for (int r = 0; r < 4; ++r) u.us[r] = f2bf(acc[mi][ni][r] * alpha + bvv);
        *(unsigned long long*)(Cc + bb * 4194304 + (long)ng * 2048 + t) = u.ll;
      } else if constexpr (CMODE == 1) {
        u16* Cc = (u16*)Cv + (long)bz * bsC;
#pragma unroll
        for (int r = 0; r < 4; ++r)
          Cc[(long)(mg + r) * ldc + ng] = f2bf(acc[mi][ni][r] * alpha + bvv);
      } else {
        float* Cf = (float*)Cv + (long)bz * bsC;
#pragma unroll
        for (int r = 0; r < 4; ++r)
          Cf[(long)(mg + r) * ldc + ng] = acc[mi][ni][r] * alpha + bvv;
      }
    }
  }
}

// ---------------- R11 1-barrier/K-tile kernel, NH=1 (final projection) ----------
__global__ __launch_bounds__(512, 2) void gemmNT1(const u16* __restrict__ A,
                                                  const u16* __restrict__ B,
                                                  float* __restrict__ Cf,
                                                  const float* __restrict__ bias,
                                                  int K, int lda, int ldb, int ldc)
{
  __shared__ u16 sm[65536];
  const int m0 = blockIdx.y * 256, n0 = blockIdx.x * 128;
  const int tid = threadIdx.x, lane = tid & 63, w = tid >> 6;
  const int wmr = w >> 2, wnr = w & 3;
  const int fr = lane & 15, ko = lane >> 4;

  f32x4 acc[8][2] = {};
  bf16x8 afA[8], afB[8], bfA[4];

  auto STAGE = [&](int dbuf, int half, int t, bool isA) {
    const u16* src = isA ? A : B;
    const int ld = isA ? lda : ldb;
    const int r0 = (isA ? m0 : n0) + half * 128;
    u16* lb = sm + (isA ? 0 : 32768) + dbuf * 16384 + half * 8192;
#pragma unroll
    for (int q = 0; q < 2; ++q) {
      const int slot = q * 512 + w * 64 + lane;
      const int rl = slot >> 3, cc = slot & 7;
      const int c = cc ^ (rl & 7);
      __builtin_amdgcn_global_load_lds(
          (g_void*)(src + (long)(r0 + rl) * ld + t * 64 + c * 8),
          (lds_void*)(lb + q * 4096 + w * 512), 16, 0, 0);
    }
  };
  auto LDA_f = [&](bf16x8* dst, int dbuf, int mh) {
#pragma unroll
    for (int mi = 0; mi < 4; ++mi)
#pragma unroll
      for (int kk = 0; kk < 2; ++kk) {
        const int r = wmr * 128 + mh * 64 + mi * 16 + fr;
        const int c = kk * 4 + ko;
        dst[mi * 2 + kk] = *(const bf16x8*)(sm + dbuf * 16384 + r * 64 + ((c ^ (r & 7)) * 8));
      }
  };
  auto LDB_f = [&](bf16x8* dst, int dbuf) {
#pragma unroll
    for (int ni = 0; ni < 2; ++ni)
#pragma unroll
      for (int kk = 0; kk < 2; ++kk) {
        const int r = wnr * 32 + ni * 16 + fr;
        const int c = kk * 4 + ko;
        dst[ni * 2 + kk] = *(const bf16x8*)(sm + 32768 + dbuf * 16384 + r * 64 + ((c ^ (r & 7)) * 8));
      }
  };
  auto MM = [&](const bf16x8* af, const bf16x8* bf, int mb) {
    __builtin_amdgcn_s_setprio(1);
#pragma unroll
    for (int mi = 0; mi < 4; ++mi)
#pragma unroll
      for (int ni = 0; ni < 2; ++ni)
#pragma unroll
        for (int kk = 0; kk < 2; ++kk)
          acc[mb + mi][ni] = __builtin_amdgcn_mfma_f32_16x16x32_bf16(
              af[mi * 2 + kk], bf[ni * 2 + kk], acc[mb + mi][ni], 0, 0, 0);
    __builtin_amdgcn_s_setprio(0);
  };

  const int nt = K >> 6;
  STAGE(0, 0, 0, true); STAGE(0, 1, 0, true); STAGE(0, 0, 0, false);
  asm volatile("s_waitcnt vmcnt(0)" ::: "memory");
  asm volatile("s_barrier" ::: "memory");

  for (int t = 0; t < nt; ++t) {
    const int d = t & 1;
    const bool pre = (t + 1 < nt);
    LDA_f(afA, d, 0); LDB_f(bfA, d);
    if (pre) { STAGE(d ^ 1, 0, t + 1, true); STAGE(d ^ 1, 1, t + 1, true); }
    MM(afA, bfA, 0);
    LDA_f(afB, d, 1);
    if (pre) STAGE(d ^ 1, 0, t + 1, false);
    MM(afB, bfA, 4);
    asm volatile("s_waitcnt vmcnt(0)" ::: "memory");
    asm volatile("s_barrier" ::: "memory");
  }

  const int col = lane & 15, rb = (lane >> 4) * 4;
#pragma unroll
  for (int mi = 0; mi < 8; ++mi)
#pragma unroll
    for (int ni = 0; ni < 2; ++ni) {
      const int mg = m0 + wmr * 128 + mi * 16 + rb;
      const int ng = n0 + wnr * 32 + ni * 16 + col;
      const float bvv = bias[ng];
#pragma unroll
      for (int r = 0; r < 4; ++r)
        Cf[(long)(mg + r) * ldc + ng] = acc[mi][ni][r] + bvv;
    }
}

// ---------------- row softmax: fp32 scores row (2048) -> bf16 P in-place --------
__global__ __launch_bounds__(256) void softmax_rows(float* __restrict__ Sc) {
  const int tid = threadIdx.x;
  const long row = blockIdx.x;
  float* srow = Sc + row * 2048;
  const float4 v0 = ((const float4*)srow)[tid * 2];
  const float4 v1 = ((const float4*)srow)[tid * 2 + 1];
  float mx = fmaxf(fmaxf(fmaxf(v0.x, v0.y), fmaxf(v0.z, v0.w)),
                   fmaxf(fmaxf(v1.x, v1.y), fmaxf(v1.z, v1.w)));
  __shared__ float red[8];
  const int lane = tid & 63, wid = tid >> 6;
#pragma unroll
  for (int off = 32; off; off >>= 1) mx = fmaxf(mx, __shfl_down(mx, off));
  if (!lane) red[wid] = mx;
  __syncthreads();
  mx = fmaxf(fmaxf(red[0], red[1]), fmaxf(red[2], red[3]));
  float e[8];
  e[0] = __expf(v0.x - mx); e[1] = __expf(v0.y - mx);
  e[2] = __expf(v0.z - mx); e[3] = __expf(v0.w - mx);
  e[4] = __expf(v1.x - mx); e[5] = __expf(v1.y - mx);
  e[6] = __expf(v1.z - mx); e[7] = __expf(v1.w - mx);
  float s = e[0] + e[1] + e[2] + e[3] + e[4] + e[5] + e[6] + e[7];
#pragma unroll
  for (int off = 32; off; off >>= 1) s += __shfl_down(s, off);
  if (!lane) red[4 + wid] = s;
  __syncthreads();
  s = red[4] + red[5] + red[6] + red[7];
  const float inv = 1.0f / s;
  union { u16 us[8]; int4 v; } u;
#pragma unroll
  for (int j = 0; j < 8; ++j) u.us[j] = f2bf(e[j] * inv);
  ((int4*)srow)[tid] = u.v;
}

extern "C" void kernel_launch(void* const* d_in, const int* in_sizes, int n_in,
                              void* d_out, int out_size, void* d_ws, size_t ws_size,
                              hipStream_t stream) {
  const float* X  = (const float*)d_in[0];
  const float* Wq = (const float*)d_in[1];
  const float* bq = (const float*)d_in[2];
  const float* Wk = (const float*)d_in[3];
  const float* bk = (const float*)d_in[4];
  const float* Wv = (const float*)d_in[5];
  const float* bv = (const float*)d_in[6];
  const float* Wo = (const float*)d_in[7];
  const float* bo = (const float*)d_in[8];
  float* out = (float*)d_out;

  char* w = (char*)d_ws;
  u16* Xb  = (u16*)w; w += (size_t)8192 * 1024 * 2;
  u16* Wqb = (u16*)w; w += (size_t)2048 * 1024 * 2;
  u16* Wkb = (u16*)w; w += (size_t)2048 * 1024 * 2;
  u16* Wvb = (u16*)w; w += (size_t)2048 * 1024 * 2;
  u16* Wob = (u16*)w; w += (size_t)1024 * 2048 * 2;
  u16* Qb  = (u16*)w; w += (size_t)8192 * 2048 * 2;
  u16* Kb  = (u16*)w; w += (size_t)8192 * 2048 * 2;
  u16* Vt  = (u16*)w; w += (size_t)8192 * 2048 * 2;   // [4][2048 d][2048 t]
  u16* AO  = (u16*)w; w += (size_t)8192 * 2048 * 2;
  float* Sc = (float*)w; w += (size_t)4 * 2048 * 2048 * 4;
  if ((size_t)(w - (char*)d_ws) > ws_size) return;

  cvt_f32_bf16<<<8192, 256, 0, stream>>>(X,  Xb,  8192 * 1024 / 4);
  cvt_f32_bf16<<<2048, 256, 0, stream>>>(Wq, Wqb, 2048 * 1024 / 4);
  cvt_f32_bf16<<<2048, 256, 0, stream>>>(Wk, Wkb, 2048 * 1024 / 4);
  cvt_f32_bf16<<<2048, 256, 0, stream>>>(Wv, Wvb, 2048 * 1024 / 4);
  cvt_f32_bf16<<<2048, 256, 0, stream>>>(Wo, Wob, 1024 * 2048 / 4);

  // projections: M=8192, N=2048, K=1024
  gemm8p<1, true><<<dim3(8, 32, 1), 512, 0, stream>>>(Xb, Wqb, Qb, bq,
      1024, 1024, 1024, 2048, 0, 0, 0, 1.0f);
  gemm8p<1, true><<<dim3(8, 32, 1), 512, 0, stream>>>(Xb, Wkb, Kb, bk,
      1024, 1024, 1024, 2048, 0, 0, 0, 1.0f);
  gemm8p<2, true><<<dim3(8, 32, 1), 512, 0, stream>>>(Xb, Wvb, Vt, bv,
      1024, 1024, 1024, 0, 0, 0, 0, 1.0f);

  // scores: per-batch 2048x2048, K=2048, alpha = 1/sqrt(1024)
  gemm8p<0, false><<<dim3(8, 8, 4), 512, 0, stream>>>(Qb, Kb, Sc, nullptr,
      2048, 2048, 2048, 2048, 4194304, 4194304, 4194304, 0.03125f);

  softmax_rows<<<8192, 256, 0, stream>>>(Sc);

  // O = P @ Vt^T : A = bf16 P view of Sc (lda 4096)
  gemm8p<1, false><<<dim3(8, 8, 4), 512, 0, stream>>>((u16*)Sc, Vt, AO, nullptr,
      2048, 4096, 2048, 2048, 8388608, 4194304, 4194304, 1.0f);

  // out = AO @ Wo^T + bo : M=8192, N=1024, K=2048, fp32 out (256x128 tiles)
  gemmNT1<<<dim3(8, 32, 1), 512, 0, stream>>>(AO, Wob, out, bo,
      2048, 2048, 2048, 1024);
}

// Round 15
// 323.423 us; speedup vs baseline: 2.3379x; 1.6948x over previous
//
#include <hip/hip_runtime.h>

// ComplexAttention: B=4, S=2048, D=1024. Reduces to single-head attention with
// head_dim 2*D=2048:  Q/K/V = X@W^T+b ; S = Q@K^T/32 ; P = softmax(S) ; O = P@V ;
// out = O@Wo^T + bo.
// R15: R14's hoisted-addressing kernel with the staging-destination constants
// FIXED (R14 halved every LDS dest offset -- bytes-vs-u16 slip: correct layout is
// u16 offset half*8192 + q*4096 + w*512, R14 wrote half*4096 + q*2048 + w*256 ->
// overlapping quarters -> absmax 1903).  Schedule = R11's proven-safe 1-barrier/
// K-tile with same-phase reads (cross-phase read-ahead spills: R3/R7/R13).

typedef short  bf16x8 __attribute__((ext_vector_type(8)));
typedef float  f32x4  __attribute__((ext_vector_type(4)));
typedef unsigned short u16;

typedef __attribute__((address_space(3))) void       lds_void;
typedef const __attribute__((address_space(1))) void g_void;

__device__ __forceinline__ u16 f2bf(float f) {
  union { float f; unsigned u; } v; v.f = f;
  unsigned r = v.u + 0x7FFFu + ((v.u >> 16) & 1u);   // round-to-nearest-even
  return (u16)(r >> 16);
}

// ---------------- fp32 -> bf16 convert (vectorized) ----------------
__global__ __launch_bounds__(256) void cvt_f32_bf16(const float* __restrict__ in,
                                                    u16* __restrict__ out, int n4) {
  int i = blockIdx.x * 256 + threadIdx.x;
  if (i >= n4) return;
  const float4 v = ((const float4*)in)[i];
  union { u16 us[4]; unsigned long long ll; } u;
  u.us[0] = f2bf(v.x); u.us[1] = f2bf(v.y); u.us[2] = f2bf(v.z); u.us[3] = f2bf(v.w);
  ((unsigned long long*)out)[i] = u.ll;
}

// ---------------- 256x(NH*128) NT GEMM, 1 barrier/K-tile, hoisted addressing ----
// C[m,n] = alpha * sum_k A[m,k]*B[n,k] (+ bias[n]).  A,B bf16 row-major (K contig).
// CMODE: 0 = fp32 C, 1 = bf16 C, 2 = bf16 transposed-V write Vt[b][n][t].
// 512 thr = 8 waves (2M x 4N); BK=64; LDS: A [2][256][64]u16 @0, B [2][..][64] @32768.
// LDS u16 layout per (operand, dbuf): half*8192 + q*4096 + w*512 + lane*8 (16B/lane);
// swizzle slot (c^(r&7)) loop-invariant per lane -> 2 read bases/operand + const
// offsets.  Safety (R11, ref-passed): per K-tile segment {reads+MMs; stage other
// buf; own vmcnt(0); BAR}.
template<int CMODE, bool BIAS, int NH>
__global__ __launch_bounds__(512, 2) void gemmK(const u16* __restrict__ A,
                                                const u16* __restrict__ B,
                                                void* __restrict__ Cv,
                                                const float* __restrict__ bias,
                                                int K, int lda, int ldb, int ldc,
                                                long bsA, long bsB, long bsC,
                                                float alpha)
{
  __shared__ u16 sm[65536];
  const int bz = blockIdx.z;
  const u16* Ab = A + (long)bz * bsA;
  const u16* Bb = B + (long)bz * bsB;
  const int m0 = blockIdx.y * 256, n0 = blockIdx.x * (NH * 128);
  const int tid = threadIdx.x, lane = tid & 63, w = tid >> 6;
  const int wmr = w >> 2, wnr = w & 3;
  const int fr = lane & 15, ko = lane >> 4;

  f32x4 acc[8][2 * NH] = {};
  bf16x8 afA[8], afB[8], bfA[4], bfB[4];

  // ---- hoisted LDS read bases (u16 units; loop-invariant per lane) ----
  const u16* aP0 = sm + wmr * 8192 + fr * 64 + (((0 + ko) ^ (fr & 7)) * 8);  // kk=0
  const u16* aP1 = sm + wmr * 8192 + fr * 64 + (((4 + ko) ^ (fr & 7)) * 8);  // kk=1
  const u16* bP0 = sm + 32768 + wnr * (NH * 32) * 64 + fr * 64 + (((0 + ko) ^ (fr & 7)) * 8);
  const u16* bP1 = sm + 32768 + wnr * (NH * 32) * 64 + fr * 64 + (((4 + ko) ^ (fr & 7)) * 8);

// frag reads: all offsets compile-time (D,MH,NHh literals; mi,ni unrolled)
#define LDAf(dst, D, MH)                                                        \
  { _Pragma("unroll") for (int mi = 0; mi < 4; ++mi) {                          \
      dst[mi * 2 + 0] = *(const bf16x8*)(aP0 + (D) * 16384 + (MH) * 4096 + mi * 1024); \
      dst[mi * 2 + 1] = *(const bf16x8*)(aP1 + (D) * 16384 + (MH) * 4096 + mi * 1024); } }
#define LDBf(dst, D, NHh)                                                       \
  { _Pragma("unroll") for (int ni = 0; ni < 2; ++ni) {                          \
      dst[ni * 2 + 0] = *(const bf16x8*)(bP0 + (D) * 16384 + (NHh) * 2048 + ni * 1024); \
      dst[ni * 2 + 1] = *(const bf16x8*)(bP1 + (D) * 16384 + (NHh) * 2048 + ni * 1024); } }

  // ---- hoisted staging pointers: lane's 16B chunk, row rl = q*64 + w*8 + (lane>>3),
  //      pre-swizzled src col c = ((lane&7) ^ (lane>>3)) * 8  (q/half-invariant) ----
  const int lrow = w * 8 + (lane >> 3);
  const int c8 = ((lane & 7) ^ (lane >> 3)) * 8;
  const long dA = (long)lda * 64, dB = (long)ldb * 64;
  const u16* pA00 = Ab + (long)(m0 + lrow) * lda + c8;       // half0,q0
  const u16* pA01 = pA00 + dA;                               // half0,q1 (+64 rows)
  const u16* pA10 = pA00 + 2 * dA;                           // half1,q0
  const u16* pA11 = pA00 + 3 * dA;                           // half1,q1
  const u16* pB00 = Bb + (long)(n0 + lrow) * ldb + c8;
  const u16* pB01 = pB00 + dB;
  const u16* pB10 = pB00 + 2 * dB;                           // NH==2 only
  const u16* pB11 = pB00 + 3 * dB;
  u16* dstB = sm + w * 512;                                  // + const per call

#define STG(ptr, CONSTOFF)                                                      \
  __builtin_amdgcn_global_load_lds((g_void*)(ptr), (lds_void*)(dstB + (CONSTOFF)), 16, 0, 0);
  // dest const (u16): (isA?0:32768) + D*16384 + HALF*8192 + Q*4096
#define STG_A(D) { STG(pA00, (D)*16384 + 0)        STG(pA01, (D)*16384 + 4096)  \
                   STG(pA10, (D)*16384 + 8192)     STG(pA11, (D)*16384 + 12288) \
                   pA00 += 64; pA01 += 64; pA10 += 64; pA11 += 64; }
#define STG_B2(D) { STG(pB00, 32768 + (D)*16384 + 0)    STG(pB01, 32768 + (D)*16384 + 4096)  \
                    STG(pB10, 32768 + (D)*16384 + 8192) STG(pB11, 32768 + (D)*16384 + 12288) \
                    pB00 += 64; pB01 += 64; pB10 += 64; pB11 += 64; }
#define STG_B1(D) { STG(pB00, 32768 + (D)*16384 + 0)    STG(pB01, 32768 + (D)*16384 + 4096)  \
                    pB00 += 64; pB01 += 64; }

  auto MM = [&](const bf16x8* af, const bf16x8* bf, int mb, int nb) {
    __builtin_amdgcn_s_setprio(1);
#pragma unroll
    for (int mi = 0; mi < 4; ++mi)
#pragma unroll
      for (int ni = 0; ni < 2; ++ni)
#pragma unroll
        for (int kk = 0; kk < 2; ++kk)
          acc[mb + mi][nb + ni] = __builtin_amdgcn_mfma_f32_16x16x32_bf16(
              af[mi * 2 + kk], bf[ni * 2 + kk], acc[mb + mi][nb + ni], 0, 0, 0);
    __builtin_amdgcn_s_setprio(0);
  };

// one K-tile on buffer D; stages next tile into buffer D^1 when SEN
#define KTILE2(D, SEN)                                                          \
  { LDAf(afA, D, 0) LDBf(bfA, D, 0)                                             \
    if (SEN) { STG_A(D ^ 1) }                                                   \
    MM(afA, bfA, 0, 0);                                                         \
    LDBf(bfB, D, 1)                                                             \
    if (SEN) { STG_B2(D ^ 1) }                                                  \
    MM(afA, bfB, 0, 2);                                                         \
    LDAf(afB, D, 1)                                                             \
    MM(afB, bfB, 4, 2);                                                         \
    MM(afB, bfA, 4, 0);                                                         \
    asm volatile("s_waitcnt vmcnt(0)" ::: "memory");                            \
    asm volatile("s_barrier" ::: "memory"); }
#define KTILE1(D, SEN)                                                          \
  { LDAf(afA, D, 0) LDBf(bfA, D, 0)                                             \
    if (SEN) { STG_A(D ^ 1) }                                                   \
    MM(afA, bfA, 0, 0);                                                         \
    LDAf(afB, D, 1)                                                             \
    if (SEN) { STG_B1(D ^ 1) }                                                  \
    MM(afB, bfA, 4, 0);                                                         \
    asm volatile("s_waitcnt vmcnt(0)" ::: "memory");                            \
    asm volatile("s_barrier" ::: "memory"); }

  const int nt = K >> 6, niter = nt >> 1;

  // prologue: tile 0 -> buf0; own-drain; barrier.
  STG_A(0)
  if constexpr (NH == 2) { STG_B2(0) } else { STG_B1(0) }
  asm volatile("s_waitcnt vmcnt(0)" ::: "memory");
  asm volatile("s_barrier" ::: "memory");

  for (int j = 0; j < niter; ++j) {
    const bool pre = (j + 1 < niter);
    if constexpr (NH == 2) {
      KTILE2(0, true)          // tile 2j   (buf0), stages 2j+1 -> buf1
      KTILE2(1, pre)           // tile 2j+1 (buf1), stages 2j+2 -> buf0
    } else {
      KTILE1(0, true)
      KTILE1(1, pre)
    }
  }

  // epilogue: C/D frag layout col=lane&15, row=(lane>>4)*4+r  (m89-verified)
  const int col = lane & 15, rb = (lane >> 4) * 4;
#pragma unroll
  for (int mi = 0; mi < 8; ++mi) {
#pragma unroll
    for (int ni = 0; ni < 2 * NH; ++ni) {
      const int mg = m0 + wmr * 128 + mi * 16 + rb;
      const int ng = n0 + wnr * (NH * 32) + ni * 16 + col;
      const float bvv = BIAS ? bias[ng] : 0.0f;
      if constexpr (CMODE == 2) {
        u16* Cc = (u16*)Cv;
        const long bb = mg >> 11;
        const int  t  = mg & 2047;
        union { u16 us[4]; unsigned long long ll; } u;
#pragma unroll
        for (int r = 0; r < 4; ++r) u.us[r] = f2bf(acc[mi][ni][r] * alpha + bvv);
        *(unsigned long long*)(Cc + bb * 4194304 + (long)ng * 2048 + t) = u.ll;
      } else if constexpr (CMODE == 1) {
        u16* Cc = (u16*)Cv + (long)bz * bsC;
#pragma unroll
        for (int r = 0; r < 4; ++r)
          Cc[(long)(mg + r) * ldc + ng] = f2bf(acc[mi][ni][r] * alpha + bvv);
      } else {
        float* Cf = (float*)Cv + (long)bz * bsC;
#pragma unroll
        for (int r = 0; r < 4; ++r)
          Cf[(long)(mg + r) * ldc + ng] = acc[mi][ni][r] * alpha + bvv;
      }
    }
  }
#undef LDAf
#undef LDBf
#undef STG
#undef STG_A
#undef STG_B2
#undef STG_B1
#undef KTILE2
#undef KTILE1
}

// ---------------- row softmax: fp32 scores row (2048) -> bf16 P in-place --------
__global__ __launch_bounds__(256) void softmax_rows(float* __restrict__ Sc) {
  const int tid = threadIdx.x;
  const long row = blockIdx.x;
  float* srow = Sc + row * 2048;
  const float4 v0 = ((const float4*)srow)[tid * 2];
  const float4 v1 = ((const float4*)srow)[tid * 2 + 1];
  float mx = fmaxf(fmaxf(fmaxf(v0.x, v0.y), fmaxf(v0.z, v0.w)),
                   fmaxf(fmaxf(v1.x, v1.y), fmaxf(v1.z, v1.w)));
  __shared__ float red[8];
  const int lane = tid & 63, wid = tid >> 6;
#pragma unroll
  for (int off = 32; off; off >>= 1) mx = fmaxf(mx, __shfl_down(mx, off));
  if (!lane) red[wid] = mx;
  __syncthreads();
  mx = fmaxf(fmaxf(red[0], red[1]), fmaxf(red[2], red[3]));
  float e[8];
  e[0] = __expf(v0.x - mx); e[1] = __expf(v0.y - mx);
  e[2] = __expf(v0.z - mx); e[3] = __expf(v0.w - mx);
  e[4] = __expf(v1.x - mx); e[5] = __expf(v1.y - mx);
  e[6] = __expf(v1.z - mx); e[7] = __expf(v1.w - mx);
  float s = e[0] + e[1] + e[2] + e[3] + e[4] + e[5] + e[6] + e[7];
#pragma unroll
  for (int off = 32; off; off >>= 1) s += __shfl_down(s, off);
  if (!lane) red[4 + wid] = s;
  __syncthreads();
  s = red[4] + red[5] + red[6] + red[7];
  const float inv = 1.0f / s;
  union { u16 us[8]; int4 v; } u;
#pragma unroll
  for (int j = 0; j < 8; ++j) u.us[j] = f2bf(e[j] * inv);
  ((int4*)srow)[tid] = u.v;
}

extern "C" void kernel_launch(void* const* d_in, const int* in_sizes, int n_in,
                              void* d_out, int out_size, void* d_ws, size_t ws_size,
                              hipStream_t stream) {
  const float* X  = (const float*)d_in[0];
  const float* Wq = (const float*)d_in[1];
  const float* bq = (const float*)d_in[2];
  const float* Wk = (const float*)d_in[3];
  const float* bk = (const float*)d_in[4];
  const float* Wv = (const float*)d_in[5];
  const float* bv = (const float*)d_in[6];
  const float* Wo = (const float*)d_in[7];
  const float* bo = (const float*)d_in[8];
  float* out = (float*)d_out;

  char* w = (char*)d_ws;
  u16* Xb  = (u16*)w; w += (size_t)8192 * 1024 * 2;
  u16* Wqb = (u16*)w; w += (size_t)2048 * 1024 * 2;
  u16* Wkb = (u16*)w; w += (size_t)2048 * 1024 * 2;
  u16* Wvb = (u16*)w; w += (size_t)2048 * 1024 * 2;
  u16* Wob = (u16*)w; w += (size_t)1024 * 2048 * 2;
  u16* Qb  = (u16*)w; w += (size_t)8192 * 2048 * 2;
  u16* Kb  = (u16*)w; w += (size_t)8192 * 2048 * 2;
  u16* Vt  = (u16*)w; w += (size_t)8192 * 2048 * 2;   // [4][2048 d][2048 t]
  u16* AO  = (u16*)w; w += (size_t)8192 * 2048 * 2;
  float* Sc = (float*)w; w += (size_t)4 * 2048 * 2048 * 4;
  if ((size_t)(w - (char*)d_ws) > ws_size) return;

  cvt_f32_bf16<<<8192, 256, 0, stream>>>(X,  Xb,  8192 * 1024 / 4);
  cvt_f32_bf16<<<2048, 256, 0, stream>>>(Wq, Wqb, 2048 * 1024 / 4);
  cvt_f32_bf16<<<2048, 256, 0, stream>>>(Wk, Wkb, 2048 * 1024 / 4);
  cvt_f32_bf16<<<2048, 256, 0, stream>>>(Wv, Wvb, 2048 * 1024 / 4);
  cvt_f32_bf16<<<2048, 256, 0, stream>>>(Wo, Wob, 1024 * 2048 / 4);

  // projections: M=8192, N=2048, K=1024
  gemmK<1, true, 2><<<dim3(8, 32, 1), 512, 0, stream>>>(Xb, Wqb, Qb, bq,
      1024, 1024, 1024, 2048, 0, 0, 0, 1.0f);
  gemmK<1, true, 2><<<dim3(8, 32, 1), 512, 0, stream>>>(Xb, Wkb, Kb, bk,
      1024, 1024, 1024, 2048, 0, 0, 0, 1.0f);
  gemmK<2, true, 2><<<dim3(8, 32, 1), 512, 0, stream>>>(Xb, Wvb, Vt, bv,
      1024, 1024, 1024, 0, 0, 0, 0, 1.0f);

  // scores: per-batch 2048x2048, K=2048, alpha = 1/sqrt(1024)
  gemmK<0, false, 2><<<dim3(8, 8, 4), 512, 0, stream>>>(Qb, Kb, Sc, nullptr,
      2048, 2048, 2048, 2048, 4194304, 4194304, 4194304, 0.03125f);

  softmax_rows<<<8192, 256, 0, stream>>>(Sc);

  // O = P @ Vt^T : A = bf16 P view of Sc (lda 4096)
  gemmK<1, false, 2><<<dim3(8, 8, 4), 512, 0, stream>>>((u16*)Sc, Vt, AO, nullptr,
      2048, 4096, 2048, 2048, 8388608, 4194304, 4194304, 1.0f);

  // out = AO @ Wo^T + bo : M=8192, N=1024, K=2048, fp32 out (256x128 tiles -> 256 blocks)
  gemmK<0, true, 1><<<dim3(8, 32, 1), 512, 0, stream>>>(AO, Wob, out, bo,
      2048, 2048, 2048, 1024, 0, 0, 0, 1.0f);
}

// Round 16
// 314.855 us; speedup vs baseline: 2.4015x; 1.0272x over previous
//
#include <hip/hip_runtime.h>

// ComplexAttention: B=4, S=2048, D=1024. Reduces to single-head attention with
// head_dim 2*D=2048:  Q/K/V = X@W^T+b ; S = Q@K^T/32 ; P = softmax(S) ; O = P@V ;
// out = O@Wo^T + bo.
// R16: softmax-path traffic cut with a precision UPGRADE: Sc stored fp16 (33 MB vs
// 66 fp32), P stored fp16 (more precise than bf16), V projected to fp16, PV GEMM
// uses mfma f16 (same frag/C-D layout as bf16 -- dtype-independent, m89/m121).
// GEMM schedule = R15's (proven): 1 barrier/K-tile, same-phase reads, hoisted
// addressing.  (Schedule axis exhausted: 37-45% MfmaUtil across 6 variants;
// read-ahead spills -- acc's 128 AGPRs cap arch VGPRs at 128: R3/R7/R13.)

typedef short  bf16x8 __attribute__((ext_vector_type(8)));
typedef _Float16 f16x8 __attribute__((ext_vector_type(8)));
typedef float  f32x4  __attribute__((ext_vector_type(4)));
typedef unsigned short u16;

typedef __attribute__((address_space(3))) void       lds_void;
typedef const __attribute__((address_space(1))) void g_void;

__device__ __forceinline__ u16 f2bf(float f) {
  union { float f; unsigned u; } v; v.f = f;
  unsigned r = v.u + 0x7FFFu + ((v.u >> 16) & 1u);   // round-to-nearest-even
  return (u16)(r >> 16);
}
__device__ __forceinline__ u16 f2h(float f) {
  union { _Float16 h; u16 u; } v; v.h = (_Float16)f; // v_cvt_f16_f32 (RNE)
  return v.u;
}
__device__ __forceinline__ float h2f(u16 u) {
  union { u16 u; _Float16 h; } v; v.u = u;
  return (float)v.h;
}

// ---------------- fp32 -> bf16 convert (vectorized) ----------------
__global__ __launch_bounds__(256) void cvt_f32_bf16(const float* __restrict__ in,
                                                    u16* __restrict__ out, int n4) {
  int i = blockIdx.x * 256 + threadIdx.x;
  if (i >= n4) return;
  const float4 v = ((const float4*)in)[i];
  union { u16 us[4]; unsigned long long ll; } u;
  u.us[0] = f2bf(v.x); u.us[1] = f2bf(v.y); u.us[2] = f2bf(v.z); u.us[3] = f2bf(v.w);
  ((unsigned long long*)out)[i] = u.ll;
}

// ---------------- 256x(NH*128) NT GEMM, 1 barrier/K-tile, hoisted addressing ----
// C[m,n] = alpha * sum_k A[m,k]*B[n,k] (+ bias[n]).  A,B 16-bit row-major (K contig).
// CMODE: 0=fp32 C, 1=bf16 C, 2=fp16 transposed-V write Vt[b][n][t], 3=fp16 C.
// FT: 0 = bf16 MFMA inputs, 1 = fp16 MFMA inputs (same frag & C/D layout).
// 512 thr = 8 waves (2M x 4N); BK=64; LDS: A [2][256][64]u16 @0, B [2][..][64] @32768.
// LDS u16 layout per (operand,dbuf): half*8192 + q*4096 + w*512 + lane*8 (16B/lane);
// swizzle slot (c^(r&7)) loop-invariant per lane.  Safety (R11/R15, ref-passed):
// per K-tile segment {reads+MMs; stage other buf; own vmcnt(0); BAR}.
template<int CMODE, bool BIAS, int NH, int FT>
__global__ __launch_bounds__(512, 2) void gemmK(const u16* __restrict__ A,
                                                const u16* __restrict__ B,
                                                void* __restrict__ Cv,
                                                const float* __restrict__ bias,
                                                int K, int lda, int ldb, int ldc,
                                                long bsA, long bsB, long bsC,
                                                float alpha)
{
  __shared__ u16 sm[65536];
  const int bz = blockIdx.z;
  const u16* Ab = A + (long)bz * bsA;
  const u16* Bb = B + (long)bz * bsB;
  const int m0 = blockIdx.y * 256, n0 = blockIdx.x * (NH * 128);
  const int tid = threadIdx.x, lane = tid & 63, w = tid >> 6;
  const int wmr = w >> 2, wnr = w & 3;
  const int fr = lane & 15, ko = lane >> 4;

  f32x4 acc[8][2 * NH] = {};
  bf16x8 afA[8], afB[8], bfA[4], bfB[4];

  // ---- hoisted LDS read bases (u16 units; loop-invariant per lane) ----
  const u16* aP0 = sm + wmr * 8192 + fr * 64 + (((0 + ko) ^ (fr & 7)) * 8);  // kk=0
  const u16* aP1 = sm + wmr * 8192 + fr * 64 + (((4 + ko) ^ (fr & 7)) * 8);  // kk=1
  const u16* bP0 = sm + 32768 + wnr * (NH * 32) * 64 + fr * 64 + (((0 + ko) ^ (fr & 7)) * 8);
  const u16* bP1 = sm + 32768 + wnr * (NH * 32) * 64 + fr * 64 + (((4 + ko) ^ (fr & 7)) * 8);

// frag reads: all offsets compile-time (D,MH,NHh literals; mi,ni unrolled)
#define LDAf(dst, D, MH)                                                        \
  { _Pragma("unroll") for (int mi = 0; mi < 4; ++mi) {                          \
      dst[mi * 2 + 0] = *(const bf16x8*)(aP0 + (D) * 16384 + (MH) * 4096 + mi * 1024); \
      dst[mi * 2 + 1] = *(const bf16x8*)(aP1 + (D) * 16384 + (MH) * 4096 + mi * 1024); } }
#define LDBf(dst, D, NHh)                                                       \
  { _Pragma("unroll") for (int ni = 0; ni < 2; ++ni) {                          \
      dst[ni * 2 + 0] = *(const bf16x8*)(bP0 + (D) * 16384 + (NHh) * 2048 + ni * 1024); \
      dst[ni * 2 + 1] = *(const bf16x8*)(bP1 + (D) * 16384 + (NHh) * 2048 + ni * 1024); } }

  // ---- hoisted staging pointers: lane's 16B chunk, row rl = q*64 + w*8 + (lane>>3),
  //      pre-swizzled src col c = ((lane&7) ^ (lane>>3)) * 8  (q/half-invariant) ----
  const int lrow = w * 8 + (lane >> 3);
  const int c8 = ((lane & 7) ^ (lane >> 3)) * 8;
  const long dA = (long)lda * 64, dB = (long)ldb * 64;
  const u16* pA00 = Ab + (long)(m0 + lrow) * lda + c8;       // half0,q0
  const u16* pA01 = pA00 + dA;                               // half0,q1 (+64 rows)
  const u16* pA10 = pA00 + 2 * dA;                           // half1,q0
  const u16* pA11 = pA00 + 3 * dA;                           // half1,q1
  const u16* pB00 = Bb + (long)(n0 + lrow) * ldb + c8;
  const u16* pB01 = pB00 + dB;
  const u16* pB10 = pB00 + 2 * dB;                           // NH==2 only
  const u16* pB11 = pB00 + 3 * dB;
  u16* dstB = sm + w * 512;                                  // + const per call

#define STG(ptr, CONSTOFF)                                                      \
  __builtin_amdgcn_global_load_lds((g_void*)(ptr), (lds_void*)(dstB + (CONSTOFF)), 16, 0, 0);
  // dest const (u16): (isA?0:32768) + D*16384 + HALF*8192 + Q*4096
#define STG_A(D) { STG(pA00, (D)*16384 + 0)        STG(pA01, (D)*16384 + 4096)  \
                   STG(pA10, (D)*16384 + 8192)     STG(pA11, (D)*16384 + 12288) \
                   pA00 += 64; pA01 += 64; pA10 += 64; pA11 += 64; }
#define STG_B2(D) { STG(pB00, 32768 + (D)*16384 + 0)    STG(pB01, 32768 + (D)*16384 + 4096)  \
                    STG(pB10, 32768 + (D)*16384 + 8192) STG(pB11, 32768 + (D)*16384 + 12288) \
                    pB00 += 64; pB01 += 64; pB10 += 64; pB11 += 64; }
#define STG_B1(D) { STG(pB00, 32768 + (D)*16384 + 0)    STG(pB01, 32768 + (D)*16384 + 4096)  \
                    pB00 += 64; pB01 += 64; }

  auto MM = [&](const bf16x8* af, const bf16x8* bf, int mb, int nb) {
    __builtin_amdgcn_s_setprio(1);
#pragma unroll
    for (int mi = 0; mi < 4; ++mi)
#pragma unroll
      for (int ni = 0; ni < 2; ++ni)
#pragma unroll
        for (int kk = 0; kk < 2; ++kk) {
          if constexpr (FT == 0)
            acc[mb + mi][nb + ni] = __builtin_amdgcn_mfma_f32_16x16x32_bf16(
                af[mi * 2 + kk], bf[ni * 2 + kk], acc[mb + mi][nb + ni], 0, 0, 0);
          else
            acc[mb + mi][nb + ni] = __builtin_amdgcn_mfma_f32_16x16x32_f16(
                __builtin_bit_cast(f16x8, af[mi * 2 + kk]),
                __builtin_bit_cast(f16x8, bf[ni * 2 + kk]),
                acc[mb + mi][nb + ni], 0, 0, 0);
        }
    __builtin_amdgcn_s_setprio(0);
  };

// one K-tile on buffer D; stages next tile into buffer D^1 when SEN
#define KTILE2(D, SEN)                                                          \
  { LDAf(afA, D, 0) LDBf(bfA, D, 0)                                             \
    if (SEN) { STG_A(D ^ 1) }                                                   \
    MM(afA, bfA, 0, 0);                                                         \
    LDBf(bfB, D, 1)                                                             \
    if (SEN) { STG_B2(D ^ 1) }                                                  \
    MM(afA, bfB, 0, 2);                                                         \
    LDAf(afB, D, 1)                                                             \
    MM(afB, bfB, 4, 2);                                                         \
    MM(afB, bfA, 4, 0);                                                         \
    asm volatile("s_waitcnt vmcnt(0)" ::: "memory");                            \
    asm volatile("s_barrier" ::: "memory"); }
#define KTILE1(D, SEN)                                                          \
  { LDAf(afA, D, 0) LDBf(bfA, D, 0)                                             \
    if (SEN) { STG_A(D ^ 1) }                                                   \
    MM(afA, bfA, 0, 0);                                                         \
    LDAf(afB, D, 1)                                                             \
    if (SEN) { STG_B1(D ^ 1) }                                                  \
    MM(afB, bfA, 4, 0);                                                         \
    asm volatile("s_waitcnt vmcnt(0)" ::: "memory");                            \
    asm volatile("s_barrier" ::: "memory"); }

  const int nt = K >> 6, niter = nt >> 1;

  // prologue: tile 0 -> buf0; own-drain; barrier.
  STG_A(0)
  if constexpr (NH == 2) { STG_B2(0) } else { STG_B1(0) }
  asm volatile("s_waitcnt vmcnt(0)" ::: "memory");
  asm volatile("s_barrier" ::: "memory");

  for (int j = 0; j < niter; ++j) {
    const bool pre = (j + 1 < niter);
    if constexpr (NH == 2) {
      KTILE2(0, true)          // tile 2j   (buf0), stages 2j+1 -> buf1
      KTILE2(1, pre)           // tile 2j+1 (buf1), stages 2j+2 -> buf0
    } else {
      KTILE1(0, true)
      KTILE1(1, pre)
    }
  }

  // epilogue: C/D frag layout col=lane&15, row=(lane>>4)*4+r  (m89-verified)
  const int col = lane & 15, rb = (lane >> 4) * 4;
#pragma unroll
  for (int mi = 0; mi < 8; ++mi) {
#pragma unroll
    for (int ni = 0; ni < 2 * NH; ++ni) {
      const int mg = m0 + wmr * 128 + mi * 16 + rb;
      const int ng = n0 + wnr * (NH * 32) + ni * 16 + col;
      const float bvv = BIAS ? bias[ng] : 0.0f;
      if constexpr (CMODE == 2) {
        u16* Cc = (u16*)Cv;
        const long bb = mg >> 11;
        const int  t  = mg & 2047;
        union { u16 us[4]; unsigned long long ll; } u;
#pragma unroll
        for (int r = 0; r < 4; ++r) u.us[r] = f2h(acc[mi][ni][r] * alpha + bvv);
        *(unsigned long long*)(Cc + bb * 4194304 + (long)ng * 2048 + t) = u.ll;
      } else if constexpr (CMODE == 1 || CMODE == 3) {
        u16* Cc = (u16*)Cv + (long)bz * bsC;
#pragma unroll
        for (int r = 0; r < 4; ++r) {
          const float x = acc[mi][ni][r] * alpha + bvv;
          Cc[(long)(mg + r) * ldc + ng] = (CMODE == 1) ? f2bf(x) : f2h(x);
        }
      } else {
        float* Cf = (float*)Cv + (long)bz * bsC;
#pragma unroll
        for (int r = 0; r < 4; ++r)
          Cf[(long)(mg + r) * ldc + ng] = acc[mi][ni][r] * alpha + bvv;
      }
    }
  }
#undef LDAf
#undef LDBf
#undef STG
#undef STG_A
#undef STG_B2
#undef STG_B1
#undef KTILE2
#undef KTILE1
}

// ---------------- row softmax: fp16 scores row (2048) -> fp16 P ----------------
__global__ __launch_bounds__(256) void softmax_f16(const u16* __restrict__ Scb,
                                                   u16* __restrict__ Pb) {
  const int tid = threadIdx.x;
  const long row = blockIdx.x;
  union { int4 v; u16 us[8]; } u;
  u.v = ((const int4*)(Scb + row * 2048))[tid];
  float f[8];
#pragma unroll
  for (int j = 0; j < 8; ++j) f[j] = h2f(u.us[j]);
  float mx = f[0];
#pragma unroll
  for (int j = 1; j < 8; ++j) mx = fmaxf(mx, f[j]);
  __shared__ float red[8];
  const int lane = tid & 63, wid = tid >> 6;
#pragma unroll
  for (int off = 32; off; off >>= 1) mx = fmaxf(mx, __shfl_down(mx, off));
  if (!lane) red[wid] = mx;
  __syncthreads();
  mx = fmaxf(fmaxf(red[0], red[1]), fmaxf(red[2], red[3]));
  float e[8], s = 0.f;
#pragma unroll
  for (int j = 0; j < 8; ++j) { e[j] = __expf(f[j] - mx); s += e[j]; }
#pragma unroll
  for (int off = 32; off; off >>= 1) s += __shfl_down(s, off);
  if (!lane) red[4 + wid] = s;
  __syncthreads();
  s = red[4] + red[5] + red[6] + red[7];
  const float inv = 1.0f / s;
  union { u16 us[8]; int4 v; } o;
#pragma unroll
  for (int j = 0; j < 8; ++j) o.us[j] = f2h(e[j] * inv);
  ((int4*)(Pb + row * 2048))[tid] = o.v;
}

extern "C" void kernel_launch(void* const* d_in, const int* in_sizes, int n_in,
                              void* d_out, int out_size, void* d_ws, size_t ws_size,
                              hipStream_t stream) {
  const float* X  = (const float*)d_in[0];
  const float* Wq = (const float*)d_in[1];
  const float* bq = (const float*)d_in[2];
  const float* Wk = (const float*)d_in[3];
  const float* bk = (const float*)d_in[4];
  const float* Wv = (const float*)d_in[5];
  const float* bv = (const float*)d_in[6];
  const float* Wo = (const float*)d_in[7];
  const float* bo = (const float*)d_in[8];
  float* out = (float*)d_out;

  char* w = (char*)d_ws;
  u16* Xb  = (u16*)w; w += (size_t)8192 * 1024 * 2;
  u16* Wqb = (u16*)w; w += (size_t)2048 * 1024 * 2;
  u16* Wkb = (u16*)w; w += (size_t)2048 * 1024 * 2;
  u16* Wvb = (u16*)w; w += (size_t)2048 * 1024 * 2;
  u16* Wob = (u16*)w; w += (size_t)1024 * 2048 * 2;
  u16* Qb  = (u16*)w; w += (size_t)8192 * 2048 * 2;
  u16* Kb  = (u16*)w; w += (size_t)8192 * 2048 * 2;
  u16* Vt  = (u16*)w; w += (size_t)8192 * 2048 * 2;   // fp16 [4][2048 d][2048 t]
  u16* AO  = (u16*)w; w += (size_t)8192 * 2048 * 2;
  u16* Scb = (u16*)w; w += (size_t)8192 * 2048 * 2;   // fp16 scores
  u16* Pb  = (u16*)w; w += (size_t)8192 * 2048 * 2;   // fp16 P
  if ((size_t)(w - (char*)d_ws) > ws_size) return;

  cvt_f32_bf16<<<8192, 256, 0, stream>>>(X,  Xb,  8192 * 1024 / 4);
  cvt_f32_bf16<<<2048, 256, 0, stream>>>(Wq, Wqb, 2048 * 1024 / 4);
  cvt_f32_bf16<<<2048, 256, 0, stream>>>(Wk, Wkb, 2048 * 1024 / 4);
  cvt_f32_bf16<<<2048, 256, 0, stream>>>(Wv, Wvb, 2048 * 1024 / 4);
  cvt_f32_bf16<<<2048, 256, 0, stream>>>(Wo, Wob, 1024 * 2048 / 4);

  // projections: M=8192, N=2048, K=1024 (bf16 in; Q/K out bf16, V out fp16-transposed)
  gemmK<1, true, 2, 0><<<dim3(8, 32, 1), 512, 0, stream>>>(Xb, Wqb, Qb, bq,
      1024, 1024, 1024, 2048, 0, 0, 0, 1.0f);
  gemmK<1, true, 2, 0><<<dim3(8, 32, 1), 512, 0, stream>>>(Xb, Wkb, Kb, bk,
      1024, 1024, 1024, 2048, 0, 0, 0, 1.0f);
  gemmK<2, true, 2, 0><<<dim3(8, 32, 1), 512, 0, stream>>>(Xb, Wvb, Vt, bv,
      1024, 1024, 1024, 0, 0, 0, 0, 1.0f);

  // scores: per-batch 2048x2048, K=2048, alpha = 1/sqrt(1024) -> fp16 Sc
  gemmK<3, false, 2, 0><<<dim3(8, 8, 4), 512, 0, stream>>>(Qb, Kb, Scb, nullptr,
      2048, 2048, 2048, 2048, 4194304, 4194304, 4194304, 0.03125f);

  softmax_f16<<<8192, 256, 0, stream>>>(Scb, Pb);

  // O = P @ Vt^T : fp16 x fp16 MFMA, bf16 AO out
  gemmK<1, false, 2, 1><<<dim3(8, 8, 4), 512, 0, stream>>>(Pb, Vt, AO, nullptr,
      2048, 2048, 2048, 2048, 4194304, 4194304, 4194304, 1.0f);

  // out = AO @ Wo^T + bo : M=8192, N=1024, K=2048, fp32 out (256x128 tiles)
  gemmK<0, true, 1, 0><<<dim3(8, 32, 1), 512, 0, stream>>>(AO, Wob, out, bo,
      2048, 2048, 2048, 1024, 0, 0, 0, 1.0f);
}